// Round 21
// baseline (444.668 us; speedup 1.0000x reference)
//
#include <hip/hip_runtime.h>
#include <cmath>

typedef __bf16 bhalf;
typedef __bf16 bf16x4 __attribute__((ext_vector_type(4)));
typedef __bf16 bf16x8 __attribute__((ext_vector_type(8)));
typedef float f32x4 __attribute__((ext_vector_type(4)));

#define MFMA16(a, b, c) __builtin_amdgcn_mfma_f32_16x16x32_bf16(a, b, c, 0, 0, 0)

namespace {
constexpr int Bn = 2, Sn = 2048, Cn = 1024, Hn = 16, Dn = 64;
constexpr int Zn = Bn * Hn;     // 32
constexpr int Mn = Bn * Sn;     // 4096
}

__device__ __forceinline__ void cvt_hilo8(const float4& v0, const float4& v1,
                                          bf16x8& hi, bf16x8& lo) {
  float f[8] = {v0.x, v0.y, v0.z, v0.w, v1.x, v1.y, v1.z, v1.w};
#pragma unroll
  for (int i = 0; i < 8; ++i) {
    bhalf h = (bhalf)f[i];
    hi[i] = h;
    lo[i] = (bhalf)(f[i] - (float)h);
  }
}

// Fused q/k/v projections (R20, unchanged): grid.z selects input.
__global__ __launch_bounds__(256) void proj_qkv(
    const float* __restrict__ qin, const float* __restrict__ kin,
    const float* __restrict__ vin, const float* __restrict__ Wq,
    const float* __restrict__ Wk, const float* __restrict__ Wv,
    bhalf* __restrict__ qhH, bhalf* __restrict__ qhL,
    bhalf* __restrict__ khH, bhalf* __restrict__ khL,
    bhalf* __restrict__ vt) {
  __shared__ bhalf BsH[64][40];
  __shared__ bhalf BsL[64][40];
  const int tid = threadIdx.x;
  const int lane = tid & 63, w = tid >> 6;
  const int l15 = lane & 15, lg = lane >> 4;
  const int nB = blockIdx.x << 6, mB = blockIdx.y << 6;
  const int which = blockIdx.z;
  const float* X = (which == 0) ? qin : (which == 1) ? kin : vin;
  const float* W = (which == 0) ? Wq : (which == 1) ? Wk : Wv;
  const int row = mB + w * 16 + l15;
  f32x4 acc[4] = {};

  const int sr = tid >> 2, sc = (tid & 3) << 3;
  for (int k0 = 0; k0 < Cn; k0 += 32) {
    {
      const float* wp = W + (size_t)(nB + sr) * Cn + k0 + sc;
      float4 w0 = *(const float4*)wp;
      float4 w1 = *(const float4*)(wp + 4);
      bf16x8 h, l;
      cvt_hilo8(w0, w1, h, l);
      *(bf16x8*)&BsH[sr][sc] = h;
      *(bf16x8*)&BsL[sr][sc] = l;
    }
    __syncthreads();
    float4 a0 = *(const float4*)(X + (size_t)row * Cn + k0 + lg * 8);
    float4 a1 = *(const float4*)(X + (size_t)row * Cn + k0 + lg * 8 + 4);
    bf16x8 aH, aL;
    cvt_hilo8(a0, a1, aH, aL);
#pragma unroll
    for (int j = 0; j < 4; ++j) {
      bf16x8 bH = *(const bf16x8*)&BsH[16 * j + l15][lg * 8];
      bf16x8 bL = *(const bf16x8*)&BsL[16 * j + l15][lg * 8];
      acc[j] = MFMA16(aH, bH, acc[j]);
      acc[j] = MFMA16(aH, bL, acc[j]);
      acc[j] = MFMA16(aL, bH, acc[j]);
    }
    __syncthreads();
  }

  const int mRow = mB + w * 16 + lg * 4;
  const int hh = nB >> 6;
  if (which < 2) {
    bhalf* dst_hi = (which == 0) ? qhH : khH;
    bhalf* dst_lo = (which == 0) ? qhL : khL;
#pragma unroll
    for (int jj = 0; jj < 2; ++jj) {
      const int d1 = 16 * jj + l15;
      const float invf = 1.0f / powf(10000.0f, (float)d1 * (1.0f / 32.0f));
#pragma unroll
      for (int r = 0; r < 4; ++r) {
        const int m = mRow + r;
        const int b = m >> 11, s = m & (Sn - 1);
        float sn, cs;
        sincosf((float)s * invf, &sn, &cs);
        const float y1 = acc[jj][r], y2 = acc[jj + 2][r];
        const float o1 = y1 * cs - y2 * sn;
        const float o2 = y2 * cs + y1 * sn;
        const size_t base = (((size_t)(b * Hn + hh)) * Sn + s) * Dn;
        bhalf h1 = (bhalf)o1, h2 = (bhalf)o2;
        dst_hi[base + d1] = h1;
        dst_lo[base + d1] = (bhalf)(o1 - (float)h1);
        dst_hi[base + d1 + 32] = h2;
        dst_lo[base + d1 + 32] = (bhalf)(o2 - (float)h2);
      }
    }
  } else {
#pragma unroll
    for (int j = 0; j < 4; ++j) {
      const int d = 16 * j + l15;
#pragma unroll
      for (int r = 0; r < 4; ++r) {
        const int m = mRow + r;
        const int b = m >> 11, s = m & (Sn - 1);
        vt[(((size_t)(b * Hn + hh)) * Dn + d) * Sn + s] = (bhalf)acc[j][r];
      }
    }
  }
}

// Final projection (R20, unchanged).
__global__ __launch_bounds__(256) void proj_out(
    const bhalf* __restrict__ AH, const bhalf* __restrict__ AL,
    const float* __restrict__ W, float* __restrict__ out_f32) {
  __shared__ bhalf BsH[64][40];
  __shared__ bhalf BsL[64][40];
  const int tid = threadIdx.x;
  const int lane = tid & 63, w = tid >> 6;
  const int l15 = lane & 15, lg = lane >> 4;
  const int nB = blockIdx.x << 6, mB = blockIdx.y << 6;
  const int row = mB + w * 16 + l15;
  f32x4 acc[4] = {};

  const int sr = tid >> 2, sc = (tid & 3) << 3;
  for (int k0 = 0; k0 < Cn; k0 += 32) {
    {
      const float* wp = W + (size_t)(nB + sr) * Cn + k0 + sc;
      float4 w0 = *(const float4*)wp;
      float4 w1 = *(const float4*)(wp + 4);
      bf16x8 h, l;
      cvt_hilo8(w0, w1, h, l);
      *(bf16x8*)&BsH[sr][sc] = h;
      *(bf16x8*)&BsL[sr][sc] = l;
    }
    __syncthreads();
    bf16x8 aH = *(const bf16x8*)(AH + (size_t)row * Cn + k0 + lg * 8);
    bf16x8 aL = *(const bf16x8*)(AL + (size_t)row * Cn + k0 + lg * 8);
#pragma unroll
    for (int j = 0; j < 4; ++j) {
      bf16x8 bH = *(const bf16x8*)&BsH[16 * j + l15][lg * 8];
      bf16x8 bL = *(const bf16x8*)&BsL[16 * j + l15][lg * 8];
      acc[j] = MFMA16(aH, bH, acc[j]);
      acc[j] = MFMA16(aH, bL, acc[j]);
      acc[j] = MFMA16(aL, bH, acc[j]);
    }
    __syncthreads();
  }

  const int mRow = mB + w * 16 + lg * 4;
#pragma unroll
  for (int j = 0; j < 4; ++j) {
    const int n = nB + 16 * j + l15;
#pragma unroll
    for (int r = 0; r < 4; ++r)
      out_f32[(size_t)(mRow + r) * Cn + n] = acc[j][r];
  }
}

__device__ __forceinline__ void load_q(const bhalf* __restrict__ qhH,
                                       const bhalf* __restrict__ qhL,
                                       size_t zrow, int sBt, int l15, int lg,
                                       bf16x8 (&qH)[2][2], bf16x8 (&qL)[2][2]) {
#pragma unroll
  for (int qf = 0; qf < 2; ++qf)
#pragma unroll
    for (int sl = 0; sl < 2; ++sl) {
      const size_t off = (zrow + sBt + qf * 16 + l15) * Dn + sl * 32 + lg * 8;
      qH[qf][sl] = *(const bf16x8*)(qhH + off);
      qL[qf][sl] = *(const bf16x8*)(qhL + off);
    }
}

// Fused attention v13: R12's v9 + explicit K register double-buffer.
// cc loop unrolled by 2 with alternating kA/kB fragment sets; loads for
// chunk c+1 issue before computing chunk c (wraps 15->0, valid across taus
// since the wave's key strip repeats). Everything else identical to v9.
__global__ __launch_bounds__(256) void attn_fused(
    const bhalf* __restrict__ qhH, const bhalf* __restrict__ qhL,
    const bhalf* __restrict__ khH, const bhalf* __restrict__ khL,
    const bhalf* __restrict__ vt, float* __restrict__ attn,
    bhalf* __restrict__ ctxH, bhalf* __restrict__ ctxL) {
  __shared__ float pt[4][32][36];
  __shared__ float lsum[4][32];
  __shared__ float linv[32];

  const int tid = threadIdx.x, lane = tid & 63, w = tid >> 6;
  const int l15 = lane & 15, lg = lane >> 4;
  const int gx = blockIdx.x;
  const int z = gx & 31;
  const int gq = gx >> 5;
  const int sB0 = gq << 7;
  const int bb = z >> 4, hh = z & 15;
  const size_t zrow = (size_t)z * Sn;
  const size_t kRow = zrow * Dn;
  const int kw = w << 9;

  bf16x8 qHc[2][2], qLc[2][2], qHp[2][2], qLp[2][2];
  load_q(qhH, qhL, zrow, sB0, l15, lg, qHc, qLc);

  // K fragment pointers for this lane (per chunk c: base + c*32*Dn)
  const bhalf* kpH = khH + kRow + (size_t)(kw + l15) * Dn + lg * 8;
  const bhalf* kpL = khL + kRow + (size_t)(kw + l15) * Dn + lg * 8;
#define LOADK(dst, c)                                                        \
  {                                                                          \
    const size_t o0 = (size_t)((c) << 5) * Dn;                               \
    const size_t o1 = o0 + (size_t)16 * Dn;                                  \
    dst[0] = *(const bf16x8*)(kpH + o0);                                     \
    dst[1] = *(const bf16x8*)(kpH + o0 + 32);                                \
    dst[2] = *(const bf16x8*)(kpL + o0);                                     \
    dst[3] = *(const bf16x8*)(kpL + o0 + 32);                                \
    dst[4] = *(const bf16x8*)(kpH + o1);                                     \
    dst[5] = *(const bf16x8*)(kpH + o1 + 32);                                \
    dst[6] = *(const bf16x8*)(kpL + o1);                                     \
    dst[7] = *(const bf16x8*)(kpL + o1 + 32);                                \
  }

  bf16x8 kA[8], kB[8];
  LOADK(kA, 0);

  float invqB[2] = {0.f, 0.f};
  f32x4 acc[2][4];

#pragma unroll 1
  for (int tau = 0; tau <= 4; ++tau) {
    const bool hasA = (tau < 4), hasB = (tau > 0);
    const int sBb = sB0 + ((tau - 1) << 5);
    float sum0 = 0.f, sum1 = 0.f;
    if (hasB) {
#pragma unroll
      for (int qf = 0; qf < 2; ++qf)
#pragma unroll
        for (int g = 0; g < 4; ++g) acc[qf][g] = f32x4{0.f, 0.f, 0.f, 0.f};
    }

#pragma unroll 1
    for (int cc = 0; cc < 16; cc += 2) {
      // prefetch odd chunk while computing even, and vice versa
      LOADK(kB, cc + 1);
#pragma unroll
      for (int half = 0; half < 2; ++half) {
        const int c = cc + half;
        const bf16x8* kf = half ? kB : kA;
        const int kbc = kw + (c << 5);
#pragma unroll
        for (int t2 = 0; t2 < 2; ++t2) {
          const bf16x8 kH0 = kf[t2 * 4 + 0], kH1 = kf[t2 * 4 + 1];
          const bf16x8 kL0 = kf[t2 * 4 + 2], kL1 = kf[t2 * 4 + 3];
          if (hasA) {
#pragma unroll
            for (int qf = 0; qf < 2; ++qf) {
              f32x4 cA = {}, cB = {};
              cA = MFMA16(kH0, qHc[qf][0], cA); cA = MFMA16(kH1, qHc[qf][1], cA);
              cB = MFMA16(kL0, qHc[qf][0], cB); cB = MFMA16(kL1, qHc[qf][1], cB);
              cA = MFMA16(kH0, qLc[qf][0], cA); cA = MFMA16(kH1, qLc[qf][1], cA);
              f32x4 c2 = cA + cB;
              float s = __expf(c2[0] * 0.125f) + __expf(c2[1] * 0.125f) +
                        __expf(c2[2] * 0.125f) + __expf(c2[3] * 0.125f);
              if (qf == 0) sum0 += s; else sum1 += s;
            }
          }
          if (hasB) {
#pragma unroll
            for (int qf = 0; qf < 2; ++qf) {
              f32x4 cA = {}, cB = {};
              cA = MFMA16(kH0, qHp[qf][0], cA); cA = MFMA16(kH1, qHp[qf][1], cA);
              cB = MFMA16(kL0, qHp[qf][0], cB); cB = MFMA16(kL1, qHp[qf][1], cB);
              cA = MFMA16(kH0, qLp[qf][0], cA); cA = MFMA16(kH1, qLp[qf][1], cA);
              f32x4 c2 = cA + cB;
              f32x4 p;
#pragma unroll
              for (int r = 0; r < 4; ++r)
                p[r] = __expf(c2[r] * 0.125f) * invqB[qf];
              *(f32x4*)&pt[w][qf * 16 + l15][(t2 << 4) + (lg << 2)] = p;
            }
          }
        }
        if (half == 0) {
          // prefetch next even chunk (wraps 14->0 for next tau)
          LOADK(kA, (cc + 2) & 15);
        }
        if (hasB) {
          const int srow = lane >> 3, scol = (lane & 7) << 2;
#pragma unroll
          for (int s = 0; s < 4; ++s) {
            const int row = (s << 3) + srow;
            f32x4 vv = *(const f32x4*)&pt[w][row][scol];
            __builtin_nontemporal_store(
                vv, (f32x4*)(attn + (zrow + sBb + row) * Sn + kbc + scol));
          }
#pragma unroll
          for (int qf = 0; qf < 2; ++qf) {
            f32x4 pa = *(const f32x4*)&pt[w][qf * 16 + l15][lg << 3];
            f32x4 pc = *(const f32x4*)&pt[w][qf * 16 + l15][(lg << 3) + 4];
            bf16x8 pbv;
#pragma unroll
            for (int e = 0; e < 4; ++e) {
              pbv[e] = (bhalf)pa[e];
              pbv[4 + e] = (bhalf)pc[e];
            }
#pragma unroll
            for (int g = 0; g < 4; ++g) {
              const bf16x8 va = *(const bf16x8*)(
                  vt + ((size_t)z * Dn + g * 16 + l15) * Sn + kbc + lg * 8);
              acc[qf][g] = MFMA16(va, pbv, acc[qf][g]);
            }
          }
        }
      }
    }

    if (hasA) {
      sum0 += __shfl_xor(sum0, 16); sum0 += __shfl_xor(sum0, 32);
      sum1 += __shfl_xor(sum1, 16); sum1 += __shfl_xor(sum1, 32);
      if (lane < 16) {
        lsum[w][l15] = sum0;
        lsum[w][16 + l15] = sum1;
      }
    }
    __syncthreads();
    if (hasA && tid < 32)
      linv[tid] =
          1.0f / (lsum[0][tid] + lsum[1][tid] + lsum[2][tid] + lsum[3][tid]);
    if (hasB) {
      float* fb = (float*)&pt[w][0][0];
      float* fb0 = (float*)&pt[0][0][0];
      float* fb1 = (float*)&pt[1][0][0];
      float* fb2 = (float*)&pt[2][0][0];
      float* fb3 = (float*)&pt[3][0][0];
#pragma unroll
      for (int qf = 0; qf < 2; ++qf) {
#pragma unroll
        for (int g = 0; g < 4; ++g)
#pragma unroll
          for (int r = 0; r < 4; ++r)
            fb[l15 * 72 + g * 16 + lg * 4 + r] = acc[qf][g][r];
        __syncthreads();
        {
          const int qq = tid >> 4, d4 = (tid & 15) << 2;
          f32x4 rs = *(const f32x4*)&fb0[qq * 72 + d4];
          rs += *(const f32x4*)&fb1[qq * 72 + d4];
          rs += *(const f32x4*)&fb2[qq * 72 + d4];
          rs += *(const f32x4*)&fb3[qq * 72 + d4];
          const size_t off =
              ((size_t)bb * Sn + sBb + qf * 16 + qq) * Cn + hh * Dn + d4;
          bf16x4 hv, lv;
#pragma unroll
          for (int e = 0; e < 4; ++e) {
            bhalf h = (bhalf)rs[e];
            hv[e] = h;
            lv[e] = (bhalf)(rs[e] - (float)h);
          }
          *(bf16x4*)(ctxH + off) = hv;
          *(bf16x4*)(ctxL + off) = lv;
        }
        __syncthreads();
      }
    } else {
      __syncthreads();
    }
    if (hasA) {
      invqB[0] = linv[l15];
      invqB[1] = linv[16 + l15];
#pragma unroll
      for (int qf = 0; qf < 2; ++qf)
#pragma unroll
        for (int sl = 0; sl < 2; ++sl) {
          qHp[qf][sl] = qHc[qf][sl];
          qLp[qf][sl] = qLc[qf][sl];
        }
      if (tau < 3)
        load_q(qhH, qhL, zrow, sB0 + ((tau + 1) << 5), l15, lg, qHc, qLc);
    }
  }
#undef LOADK
}

extern "C" void kernel_launch(void* const* d_in, const int* in_sizes, int n_in,
                              void* d_out, int out_size, void* d_ws, size_t ws_size,
                              hipStream_t stream) {
  const float* q = (const float*)d_in[0];
  const float* k = (const float*)d_in[1];
  const float* v = (const float*)d_in[2];
  const float* Wq = (const float*)d_in[3];
  const float* Wk = (const float*)d_in[4];
  const float* Wv = (const float*)d_in[5];
  const float* Wo = (const float*)d_in[6];

  float* out = (float*)d_out;                       // [B,S,C] 4M f32
  float* attn = out + (size_t)Mn * Cn;              // [B,H,S,S] 134M f32
  bhalf* vt = (bhalf*)d_out;                        // stash V^T (8MB) in out region

  bhalf* qhH = (bhalf*)d_ws;                        // 6 x 8MB = 48MB ws
  bhalf* qhL = qhH + (size_t)Mn * Cn;
  bhalf* khH = qhL + (size_t)Mn * Cn;
  bhalf* khL = khH + (size_t)Mn * Cn;
  bhalf* ctxH = khL + (size_t)Mn * Cn;
  bhalf* ctxL = ctxH + (size_t)Mn * Cn;

  dim3 gP3(Cn / 64, Mn / 64, 3);  // fused q/k/v projections, one launch
  proj_qkv<<<gP3, 256, 0, stream>>>(q, k, v, Wq, Wk, Wv, qhH, qhL, khH, khL, vt);

  attn_fused<<<Zn * (Sn / 128), 256, 0, stream>>>(qhH, qhL, khH, khL, vt, attn,
                                                  ctxH, ctxL);

  dim3 gP(Cn / 64, Mn / 64);
  proj_out<<<gP, 256, 0, stream>>>(ctxH, ctxL, Wo, out);
}

// Round 22
// 408.003 us; speedup vs baseline: 1.0899x; 1.0899x over previous
//
#include <hip/hip_runtime.h>
#include <cmath>

typedef __bf16 bhalf;
typedef __bf16 bf16x4 __attribute__((ext_vector_type(4)));
typedef __bf16 bf16x8 __attribute__((ext_vector_type(8)));
typedef float f32x4 __attribute__((ext_vector_type(4)));

#define MFMA16(a, b, c) __builtin_amdgcn_mfma_f32_16x16x32_bf16(a, b, c, 0, 0, 0)

namespace {
constexpr int Bn = 2, Sn = 2048, Cn = 1024, Hn = 16, Dn = 64;
constexpr int Zn = Bn * Hn;     // 32
constexpr int Mn = Bn * Sn;     // 4096
}

__device__ __forceinline__ void cvt_hilo8(const float4& v0, const float4& v1,
                                          bf16x8& hi, bf16x8& lo) {
  float f[8] = {v0.x, v0.y, v0.z, v0.w, v1.x, v1.y, v1.z, v1.w};
#pragma unroll
  for (int i = 0; i < 8; ++i) {
    bhalf h = (bhalf)f[i];
    hi[i] = h;
    lo[i] = (bhalf)(f[i] - (float)h);
  }
}

// Fused q/k/v projections (R20): grid.z selects input. NEW: for Q (z=0),
// the 1/sqrt(d)=0.125 scale is folded into the RoPE output before the hi/lo
// split, so attn's QK^T directly yields scaled logits (saves a v_mul on the
// exp critical path in both attn passes).
__global__ __launch_bounds__(256) void proj_qkv(
    const float* __restrict__ qin, const float* __restrict__ kin,
    const float* __restrict__ vin, const float* __restrict__ Wq,
    const float* __restrict__ Wk, const float* __restrict__ Wv,
    bhalf* __restrict__ qhH, bhalf* __restrict__ qhL,
    bhalf* __restrict__ khH, bhalf* __restrict__ khL,
    bhalf* __restrict__ vt) {
  __shared__ bhalf BsH[64][40];
  __shared__ bhalf BsL[64][40];
  const int tid = threadIdx.x;
  const int lane = tid & 63, w = tid >> 6;
  const int l15 = lane & 15, lg = lane >> 4;
  const int nB = blockIdx.x << 6, mB = blockIdx.y << 6;
  const int which = blockIdx.z;
  const float* X = (which == 0) ? qin : (which == 1) ? kin : vin;
  const float* W = (which == 0) ? Wq : (which == 1) ? Wk : Wv;
  const int row = mB + w * 16 + l15;
  f32x4 acc[4] = {};

  const int sr = tid >> 2, sc = (tid & 3) << 3;
  for (int k0 = 0; k0 < Cn; k0 += 32) {
    {
      const float* wp = W + (size_t)(nB + sr) * Cn + k0 + sc;
      float4 w0 = *(const float4*)wp;
      float4 w1 = *(const float4*)(wp + 4);
      bf16x8 h, l;
      cvt_hilo8(w0, w1, h, l);
      *(bf16x8*)&BsH[sr][sc] = h;
      *(bf16x8*)&BsL[sr][sc] = l;
    }
    __syncthreads();
    float4 a0 = *(const float4*)(X + (size_t)row * Cn + k0 + lg * 8);
    float4 a1 = *(const float4*)(X + (size_t)row * Cn + k0 + lg * 8 + 4);
    bf16x8 aH, aL;
    cvt_hilo8(a0, a1, aH, aL);
#pragma unroll
    for (int j = 0; j < 4; ++j) {
      bf16x8 bH = *(const bf16x8*)&BsH[16 * j + l15][lg * 8];
      bf16x8 bL = *(const bf16x8*)&BsL[16 * j + l15][lg * 8];
      acc[j] = MFMA16(aH, bH, acc[j]);
      acc[j] = MFMA16(aH, bL, acc[j]);
      acc[j] = MFMA16(aL, bH, acc[j]);
    }
    __syncthreads();
  }

  const int mRow = mB + w * 16 + lg * 4;
  const int hh = nB >> 6;
  if (which < 2) {
    bhalf* dst_hi = (which == 0) ? qhH : khH;
    bhalf* dst_lo = (which == 0) ? qhL : khL;
    const float osc = (which == 0) ? 0.125f : 1.0f;  // fold 1/sqrt(d) into Q
#pragma unroll
    for (int jj = 0; jj < 2; ++jj) {
      const int d1 = 16 * jj + l15;
      const float invf = 1.0f / powf(10000.0f, (float)d1 * (1.0f / 32.0f));
#pragma unroll
      for (int r = 0; r < 4; ++r) {
        const int m = mRow + r;
        const int b = m >> 11, s = m & (Sn - 1);
        float sn, cs;
        sincosf((float)s * invf, &sn, &cs);
        const float y1 = acc[jj][r], y2 = acc[jj + 2][r];
        const float o1 = (y1 * cs - y2 * sn) * osc;
        const float o2 = (y2 * cs + y1 * sn) * osc;
        const size_t base = (((size_t)(b * Hn + hh)) * Sn + s) * Dn;
        bhalf h1 = (bhalf)o1, h2 = (bhalf)o2;
        dst_hi[base + d1] = h1;
        dst_lo[base + d1] = (bhalf)(o1 - (float)h1);
        dst_hi[base + d1 + 32] = h2;
        dst_lo[base + d1 + 32] = (bhalf)(o2 - (float)h2);
      }
    }
  } else {
#pragma unroll
    for (int j = 0; j < 4; ++j) {
      const int d = 16 * j + l15;
#pragma unroll
      for (int r = 0; r < 4; ++r) {
        const int m = mRow + r;
        const int b = m >> 11, s = m & (Sn - 1);
        vt[(((size_t)(b * Hn + hh)) * Dn + d) * Sn + s] = (bhalf)acc[j][r];
      }
    }
  }
}

// Final projection (R20, unchanged).
__global__ __launch_bounds__(256) void proj_out(
    const bhalf* __restrict__ AH, const bhalf* __restrict__ AL,
    const float* __restrict__ W, float* __restrict__ out_f32) {
  __shared__ bhalf BsH[64][40];
  __shared__ bhalf BsL[64][40];
  const int tid = threadIdx.x;
  const int lane = tid & 63, w = tid >> 6;
  const int l15 = lane & 15, lg = lane >> 4;
  const int nB = blockIdx.x << 6, mB = blockIdx.y << 6;
  const int row = mB + w * 16 + l15;
  f32x4 acc[4] = {};

  const int sr = tid >> 2, sc = (tid & 3) << 3;
  for (int k0 = 0; k0 < Cn; k0 += 32) {
    {
      const float* wp = W + (size_t)(nB + sr) * Cn + k0 + sc;
      float4 w0 = *(const float4*)wp;
      float4 w1 = *(const float4*)(wp + 4);
      bf16x8 h, l;
      cvt_hilo8(w0, w1, h, l);
      *(bf16x8*)&BsH[sr][sc] = h;
      *(bf16x8*)&BsL[sr][sc] = l;
    }
    __syncthreads();
    bf16x8 aH = *(const bf16x8*)(AH + (size_t)row * Cn + k0 + lg * 8);
    bf16x8 aL = *(const bf16x8*)(AL + (size_t)row * Cn + k0 + lg * 8);
#pragma unroll
    for (int j = 0; j < 4; ++j) {
      bf16x8 bH = *(const bf16x8*)&BsH[16 * j + l15][lg * 8];
      bf16x8 bL = *(const bf16x8*)&BsL[16 * j + l15][lg * 8];
      acc[j] = MFMA16(aH, bH, acc[j]);
      acc[j] = MFMA16(aH, bL, acc[j]);
      acc[j] = MFMA16(aL, bH, acc[j]);
    }
    __syncthreads();
  }

  const int mRow = mB + w * 16 + lg * 4;
#pragma unroll
  for (int j = 0; j < 4; ++j) {
    const int n = nB + 16 * j + l15;
#pragma unroll
    for (int r = 0; r < 4; ++r)
      out_f32[(size_t)(mRow + r) * Cn + n] = acc[j][r];
  }
}

__device__ __forceinline__ void load_q(const bhalf* __restrict__ qhH,
                                       const bhalf* __restrict__ qhL,
                                       size_t zrow, int sBt, int l15, int lg,
                                       bf16x8 (&qH)[2][2], bf16x8 (&qL)[2][2]) {
#pragma unroll
  for (int qf = 0; qf < 2; ++qf)
#pragma unroll
    for (int sl = 0; sl < 2; ++sl) {
      const size_t off = (zrow + sBt + qf * 16 + l15) * Dn + sl * 32 + lg * 8;
      qH[qf][sl] = *(const bf16x8*)(qhH + off);
      qL[qf][sl] = *(const bf16x8*)(qhL + off);
    }
}

// Fused attention v9s: R12/R20's v9 with the 0.125 scale removed (folded
// into Q at projection time). Otherwise byte-for-byte the 405.9us best.
__global__ __launch_bounds__(256) void attn_fused(
    const bhalf* __restrict__ qhH, const bhalf* __restrict__ qhL,
    const bhalf* __restrict__ khH, const bhalf* __restrict__ khL,
    const bhalf* __restrict__ vt, float* __restrict__ attn,
    bhalf* __restrict__ ctxH, bhalf* __restrict__ ctxL) {
  __shared__ float pt[4][32][36];
  __shared__ float lsum[4][32];
  __shared__ float linv[32];

  const int tid = threadIdx.x, lane = tid & 63, w = tid >> 6;
  const int l15 = lane & 15, lg = lane >> 4;
  const int gx = blockIdx.x;
  const int z = gx & 31;
  const int gq = gx >> 5;
  const int sB0 = gq << 7;
  const int bb = z >> 4, hh = z & 15;
  const size_t zrow = (size_t)z * Sn;
  const size_t kRow = zrow * Dn;
  const int kw = w << 9;

  bf16x8 qHc[2][2], qLc[2][2], qHp[2][2], qLp[2][2];
  load_q(qhH, qhL, zrow, sB0, l15, lg, qHc, qLc);

  float invqB[2] = {0.f, 0.f};
  f32x4 acc[2][4];

#pragma unroll 1
  for (int tau = 0; tau <= 4; ++tau) {
    const bool hasA = (tau < 4), hasB = (tau > 0);
    const int sBb = sB0 + ((tau - 1) << 5);
    float sum0 = 0.f, sum1 = 0.f;
    if (hasB) {
#pragma unroll
      for (int qf = 0; qf < 2; ++qf)
#pragma unroll
        for (int g = 0; g < 4; ++g) acc[qf][g] = f32x4{0.f, 0.f, 0.f, 0.f};
    }

#pragma unroll 1
    for (int cc = 0; cc < 16; ++cc) {
      const int kbc = kw + (cc << 5);
#pragma unroll
      for (int t2 = 0; t2 < 2; ++t2) {
        const int kb = kbc + (t2 << 4);
        const bhalf* kp = khH + kRow + (size_t)(kb + l15) * Dn + lg * 8;
        const bhalf* kq = khL + kRow + (size_t)(kb + l15) * Dn + lg * 8;
        bf16x8 kH0 = *(const bf16x8*)kp, kH1 = *(const bf16x8*)(kp + 32);
        bf16x8 kL0 = *(const bf16x8*)kq, kL1 = *(const bf16x8*)(kq + 32);
        if (hasA) {
#pragma unroll
          for (int qf = 0; qf < 2; ++qf) {
            f32x4 cA = {}, cB = {};
            cA = MFMA16(kH0, qHc[qf][0], cA); cA = MFMA16(kH1, qHc[qf][1], cA);
            cB = MFMA16(kL0, qHc[qf][0], cB); cB = MFMA16(kL1, qHc[qf][1], cB);
            cA = MFMA16(kH0, qLc[qf][0], cA); cA = MFMA16(kH1, qLc[qf][1], cA);
            f32x4 c = cA + cB;
            float s = __expf(c[0]) + __expf(c[1]) +
                      __expf(c[2]) + __expf(c[3]);
            if (qf == 0) sum0 += s; else sum1 += s;
          }
        }
        if (hasB) {
#pragma unroll
          for (int qf = 0; qf < 2; ++qf) {
            f32x4 cA = {}, cB = {};
            cA = MFMA16(kH0, qHp[qf][0], cA); cA = MFMA16(kH1, qHp[qf][1], cA);
            cB = MFMA16(kL0, qHp[qf][0], cB); cB = MFMA16(kL1, qHp[qf][1], cB);
            cA = MFMA16(kH0, qLp[qf][0], cA); cA = MFMA16(kH1, qLp[qf][1], cA);
            f32x4 c = cA + cB;
            f32x4 p;
#pragma unroll
            for (int r = 0; r < 4; ++r)
              p[r] = __expf(c[r]) * invqB[qf];
            *(f32x4*)&pt[w][qf * 16 + l15][(t2 << 4) + (lg << 2)] = p;
          }
        }
      }
      if (hasB) {
        const int srow = lane >> 3, scol = (lane & 7) << 2;
#pragma unroll
        for (int s = 0; s < 4; ++s) {
          const int row = (s << 3) + srow;
          f32x4 vv = *(const f32x4*)&pt[w][row][scol];
          __builtin_nontemporal_store(
              vv, (f32x4*)(attn + (zrow + sBb + row) * Sn + kbc + scol));
        }
#pragma unroll
        for (int qf = 0; qf < 2; ++qf) {
          f32x4 pa = *(const f32x4*)&pt[w][qf * 16 + l15][lg << 3];
          f32x4 pc = *(const f32x4*)&pt[w][qf * 16 + l15][(lg << 3) + 4];
          bf16x8 pbv;
#pragma unroll
          for (int e = 0; e < 4; ++e) {
            pbv[e] = (bhalf)pa[e];
            pbv[4 + e] = (bhalf)pc[e];
          }
#pragma unroll
          for (int g = 0; g < 4; ++g) {
            const bf16x8 va = *(const bf16x8*)(
                vt + ((size_t)z * Dn + g * 16 + l15) * Sn + kbc + lg * 8);
            acc[qf][g] = MFMA16(va, pbv, acc[qf][g]);
          }
        }
      }
    }

    if (hasA) {
      sum0 += __shfl_xor(sum0, 16); sum0 += __shfl_xor(sum0, 32);
      sum1 += __shfl_xor(sum1, 16); sum1 += __shfl_xor(sum1, 32);
      if (lane < 16) {
        lsum[w][l15] = sum0;
        lsum[w][16 + l15] = sum1;
      }
    }
    __syncthreads();
    if (hasA && tid < 32)
      linv[tid] =
          1.0f / (lsum[0][tid] + lsum[1][tid] + lsum[2][tid] + lsum[3][tid]);
    if (hasB) {
      float* fb = (float*)&pt[w][0][0];
      float* fb0 = (float*)&pt[0][0][0];
      float* fb1 = (float*)&pt[1][0][0];
      float* fb2 = (float*)&pt[2][0][0];
      float* fb3 = (float*)&pt[3][0][0];
#pragma unroll
      for (int qf = 0; qf < 2; ++qf) {
#pragma unroll
        for (int g = 0; g < 4; ++g)
#pragma unroll
          for (int r = 0; r < 4; ++r)
            fb[l15 * 72 + g * 16 + lg * 4 + r] = acc[qf][g][r];
        __syncthreads();
        {
          const int qq = tid >> 4, d4 = (tid & 15) << 2;
          f32x4 rs = *(const f32x4*)&fb0[qq * 72 + d4];
          rs += *(const f32x4*)&fb1[qq * 72 + d4];
          rs += *(const f32x4*)&fb2[qq * 72 + d4];
          rs += *(const f32x4*)&fb3[qq * 72 + d4];
          const size_t off =
              ((size_t)bb * Sn + sBb + qf * 16 + qq) * Cn + hh * Dn + d4;
          bf16x4 hv, lv;
#pragma unroll
          for (int e = 0; e < 4; ++e) {
            bhalf h = (bhalf)rs[e];
            hv[e] = h;
            lv[e] = (bhalf)(rs[e] - (float)h);
          }
          *(bf16x4*)(ctxH + off) = hv;
          *(bf16x4*)(ctxL + off) = lv;
        }
        __syncthreads();
      }
    } else {
      __syncthreads();
    }
    if (hasA) {
      invqB[0] = linv[l15];
      invqB[1] = linv[16 + l15];
#pragma unroll
      for (int qf = 0; qf < 2; ++qf)
#pragma unroll
        for (int sl = 0; sl < 2; ++sl) {
          qHp[qf][sl] = qHc[qf][sl];
          qLp[qf][sl] = qLc[qf][sl];
        }
      if (tau < 3)
        load_q(qhH, qhL, zrow, sB0 + ((tau + 1) << 5), l15, lg, qHc, qLc);
    }
  }
}

extern "C" void kernel_launch(void* const* d_in, const int* in_sizes, int n_in,
                              void* d_out, int out_size, void* d_ws, size_t ws_size,
                              hipStream_t stream) {
  const float* q = (const float*)d_in[0];
  const float* k = (const float*)d_in[1];
  const float* v = (const float*)d_in[2];
  const float* Wq = (const float*)d_in[3];
  const float* Wk = (const float*)d_in[4];
  const float* Wv = (const float*)d_in[5];
  const float* Wo = (const float*)d_in[6];

  float* out = (float*)d_out;                       // [B,S,C] 4M f32
  float* attn = out + (size_t)Mn * Cn;              // [B,H,S,S] 134M f32
  bhalf* vt = (bhalf*)d_out;                        // stash V^T (8MB) in out region

  bhalf* qhH = (bhalf*)d_ws;                        // 6 x 8MB = 48MB ws
  bhalf* qhL = qhH + (size_t)Mn * Cn;
  bhalf* khH = qhL + (size_t)Mn * Cn;
  bhalf* khL = khH + (size_t)Mn * Cn;
  bhalf* ctxH = khL + (size_t)Mn * Cn;
  bhalf* ctxL = ctxH + (size_t)Mn * Cn;

  dim3 gP3(Cn / 64, Mn / 64, 3);  // fused q/k/v projections, one launch
  proj_qkv<<<gP3, 256, 0, stream>>>(q, k, v, Wq, Wk, Wv, qhH, qhL, khH, khL, vt);

  attn_fused<<<Zn * (Sn / 128), 256, 0, stream>>>(qhH, qhL, khH, khL, vt, attn,
                                                  ctxH, ctxL);

  dim3 gP(Cn / 64, Mn / 64);
  proj_out<<<gP, 256, 0, stream>>>(ctxH, ctxL, Wo, out);
}

// Round 23
// 406.307 us; speedup vs baseline: 1.0944x; 1.0042x over previous
//
#include <hip/hip_runtime.h>
#include <cmath>

typedef __bf16 bhalf;
typedef __bf16 bf16x4 __attribute__((ext_vector_type(4)));
typedef __bf16 bf16x8 __attribute__((ext_vector_type(8)));
typedef float f32x4 __attribute__((ext_vector_type(4)));

#define MFMA16(a, b, c) __builtin_amdgcn_mfma_f32_16x16x32_bf16(a, b, c, 0, 0, 0)
#define EXP2(x) __builtin_amdgcn_exp2f(x)

namespace {
constexpr int Bn = 2, Sn = 2048, Cn = 1024, Hn = 16, Dn = 64;
constexpr int Zn = Bn * Hn;     // 32
constexpr int Mn = Bn * Sn;     // 4096
}

__device__ __forceinline__ void cvt_hilo8(const float4& v0, const float4& v1,
                                          bf16x8& hi, bf16x8& lo) {
  float f[8] = {v0.x, v0.y, v0.z, v0.w, v1.x, v1.y, v1.z, v1.w};
#pragma unroll
  for (int i = 0; i < 8; ++i) {
    bhalf h = (bhalf)f[i];
    hi[i] = h;
    lo[i] = (bhalf)(f[i] - (float)h);
  }
}

// Fused q/k/v projections: grid.z selects input. For Q (z=0) we fold
// 0.125*log2(e) so attn computes p = exp2(QK^T) with NO mul before
// v_exp_f32 (raw transcendental on the critical path).
__global__ __launch_bounds__(256) void proj_qkv(
    const float* __restrict__ qin, const float* __restrict__ kin,
    const float* __restrict__ vin, const float* __restrict__ Wq,
    const float* __restrict__ Wk, const float* __restrict__ Wv,
    bhalf* __restrict__ qhH, bhalf* __restrict__ qhL,
    bhalf* __restrict__ khH, bhalf* __restrict__ khL,
    bhalf* __restrict__ vt) {
  __shared__ bhalf BsH[64][40];
  __shared__ bhalf BsL[64][40];
  const int tid = threadIdx.x;
  const int lane = tid & 63, w = tid >> 6;
  const int l15 = lane & 15, lg = lane >> 4;
  const int nB = blockIdx.x << 6, mB = blockIdx.y << 6;
  const int which = blockIdx.z;
  const float* X = (which == 0) ? qin : (which == 1) ? kin : vin;
  const float* W = (which == 0) ? Wq : (which == 1) ? Wk : Wv;
  const int row = mB + w * 16 + l15;
  f32x4 acc[4] = {};

  const int sr = tid >> 2, sc = (tid & 3) << 3;
  for (int k0 = 0; k0 < Cn; k0 += 32) {
    {
      const float* wp = W + (size_t)(nB + sr) * Cn + k0 + sc;
      float4 w0 = *(const float4*)wp;
      float4 w1 = *(const float4*)(wp + 4);
      bf16x8 h, l;
      cvt_hilo8(w0, w1, h, l);
      *(bf16x8*)&BsH[sr][sc] = h;
      *(bf16x8*)&BsL[sr][sc] = l;
    }
    __syncthreads();
    float4 a0 = *(const float4*)(X + (size_t)row * Cn + k0 + lg * 8);
    float4 a1 = *(const float4*)(X + (size_t)row * Cn + k0 + lg * 8 + 4);
    bf16x8 aH, aL;
    cvt_hilo8(a0, a1, aH, aL);
#pragma unroll
    for (int j = 0; j < 4; ++j) {
      bf16x8 bH = *(const bf16x8*)&BsH[16 * j + l15][lg * 8];
      bf16x8 bL = *(const bf16x8*)&BsL[16 * j + l15][lg * 8];
      acc[j] = MFMA16(aH, bH, acc[j]);
      acc[j] = MFMA16(aH, bL, acc[j]);
      acc[j] = MFMA16(aL, bH, acc[j]);
    }
    __syncthreads();
  }

  const int mRow = mB + w * 16 + lg * 4;
  const int hh = nB >> 6;
  if (which < 2) {
    bhalf* dst_hi = (which == 0) ? qhH : khH;
    bhalf* dst_lo = (which == 0) ? qhL : khL;
    // 0.125 * log2(e): scores become log2-domain -> exp2 needs no mul
    const float osc = (which == 0) ? 0.18033688011112042f : 1.0f;
#pragma unroll
    for (int jj = 0; jj < 2; ++jj) {
      const int d1 = 16 * jj + l15;
      const float invf = 1.0f / powf(10000.0f, (float)d1 * (1.0f / 32.0f));
#pragma unroll
      for (int r = 0; r < 4; ++r) {
        const int m = mRow + r;
        const int b = m >> 11, s = m & (Sn - 1);
        float sn, cs;
        sincosf((float)s * invf, &sn, &cs);
        const float y1 = acc[jj][r], y2 = acc[jj + 2][r];
        const float o1 = (y1 * cs - y2 * sn) * osc;
        const float o2 = (y2 * cs + y1 * sn) * osc;
        const size_t base = (((size_t)(b * Hn + hh)) * Sn + s) * Dn;
        bhalf h1 = (bhalf)o1, h2 = (bhalf)o2;
        dst_hi[base + d1] = h1;
        dst_lo[base + d1] = (bhalf)(o1 - (float)h1);
        dst_hi[base + d1 + 32] = h2;
        dst_lo[base + d1 + 32] = (bhalf)(o2 - (float)h2);
      }
    }
  } else {
#pragma unroll
    for (int j = 0; j < 4; ++j) {
      const int d = 16 * j + l15;
#pragma unroll
      for (int r = 0; r < 4; ++r) {
        const int m = mRow + r;
        const int b = m >> 11, s = m & (Sn - 1);
        vt[(((size_t)(b * Hn + hh)) * Dn + d) * Sn + s] = (bhalf)acc[j][r];
      }
    }
  }
}

// Final projection (unchanged).
__global__ __launch_bounds__(256) void proj_out(
    const bhalf* __restrict__ AH, const bhalf* __restrict__ AL,
    const float* __restrict__ W, float* __restrict__ out_f32) {
  __shared__ bhalf BsH[64][40];
  __shared__ bhalf BsL[64][40];
  const int tid = threadIdx.x;
  const int lane = tid & 63, w = tid >> 6;
  const int l15 = lane & 15, lg = lane >> 4;
  const int nB = blockIdx.x << 6, mB = blockIdx.y << 6;
  const int row = mB + w * 16 + l15;
  f32x4 acc[4] = {};

  const int sr = tid >> 2, sc = (tid & 3) << 3;
  for (int k0 = 0; k0 < Cn; k0 += 32) {
    {
      const float* wp = W + (size_t)(nB + sr) * Cn + k0 + sc;
      float4 w0 = *(const float4*)wp;
      float4 w1 = *(const float4*)(wp + 4);
      bf16x8 h, l;
      cvt_hilo8(w0, w1, h, l);
      *(bf16x8*)&BsH[sr][sc] = h;
      *(bf16x8*)&BsL[sr][sc] = l;
    }
    __syncthreads();
    bf16x8 aH = *(const bf16x8*)(AH + (size_t)row * Cn + k0 + lg * 8);
    bf16x8 aL = *(const bf16x8*)(AL + (size_t)row * Cn + k0 + lg * 8);
#pragma unroll
    for (int j = 0; j < 4; ++j) {
      bf16x8 bH = *(const bf16x8*)&BsH[16 * j + l15][lg * 8];
      bf16x8 bL = *(const bf16x8*)&BsL[16 * j + l15][lg * 8];
      acc[j] = MFMA16(aH, bH, acc[j]);
      acc[j] = MFMA16(aH, bL, acc[j]);
      acc[j] = MFMA16(aL, bH, acc[j]);
    }
    __syncthreads();
  }

  const int mRow = mB + w * 16 + lg * 4;
#pragma unroll
  for (int j = 0; j < 4; ++j) {
    const int n = nB + 16 * j + l15;
#pragma unroll
    for (int r = 0; r < 4; ++r)
      out_f32[(size_t)(mRow + r) * Cn + n] = acc[j][r];
  }
}

__device__ __forceinline__ void load_q(const bhalf* __restrict__ qhH,
                                       const bhalf* __restrict__ qhL,
                                       size_t zrow, int sBt, int l15, int lg,
                                       bf16x8 (&qH)[2][2], bf16x8 (&qL)[2][2]) {
#pragma unroll
  for (int qf = 0; qf < 2; ++qf)
#pragma unroll
    for (int sl = 0; sl < 2; ++sl) {
      const size_t off = (zrow + sBt + qf * 16 + l15) * Dn + sl * 32 + lg * 8;
      qH[qf][sl] = *(const bf16x8*)(qhH + off);
      qL[qf][sl] = *(const bf16x8*)(qhL + off);
    }
}

// Fused attention v9e: v9s with exp2 (raw v_exp_f32, no preceding mul —
// log2e folded into Q). Otherwise byte-for-byte the 405.9us best.
__global__ __launch_bounds__(256) void attn_fused(
    const bhalf* __restrict__ qhH, const bhalf* __restrict__ qhL,
    const bhalf* __restrict__ khH, const bhalf* __restrict__ khL,
    const bhalf* __restrict__ vt, float* __restrict__ attn,
    bhalf* __restrict__ ctxH, bhalf* __restrict__ ctxL) {
  __shared__ float pt[4][32][36];
  __shared__ float lsum[4][32];
  __shared__ float linv[32];

  const int tid = threadIdx.x, lane = tid & 63, w = tid >> 6;
  const int l15 = lane & 15, lg = lane >> 4;
  const int gx = blockIdx.x;
  const int z = gx & 31;
  const int gq = gx >> 5;
  const int sB0 = gq << 7;
  const int bb = z >> 4, hh = z & 15;
  const size_t zrow = (size_t)z * Sn;
  const size_t kRow = zrow * Dn;
  const int kw = w << 9;

  bf16x8 qHc[2][2], qLc[2][2], qHp[2][2], qLp[2][2];
  load_q(qhH, qhL, zrow, sB0, l15, lg, qHc, qLc);

  float invqB[2] = {0.f, 0.f};
  f32x4 acc[2][4];

#pragma unroll 1
  for (int tau = 0; tau <= 4; ++tau) {
    const bool hasA = (tau < 4), hasB = (tau > 0);
    const int sBb = sB0 + ((tau - 1) << 5);
    float sum0 = 0.f, sum1 = 0.f;
    if (hasB) {
#pragma unroll
      for (int qf = 0; qf < 2; ++qf)
#pragma unroll
        for (int g = 0; g < 4; ++g) acc[qf][g] = f32x4{0.f, 0.f, 0.f, 0.f};
    }

#pragma unroll 1
    for (int cc = 0; cc < 16; ++cc) {
      const int kbc = kw + (cc << 5);
#pragma unroll
      for (int t2 = 0; t2 < 2; ++t2) {
        const int kb = kbc + (t2 << 4);
        const bhalf* kp = khH + kRow + (size_t)(kb + l15) * Dn + lg * 8;
        const bhalf* kq = khL + kRow + (size_t)(kb + l15) * Dn + lg * 8;
        bf16x8 kH0 = *(const bf16x8*)kp, kH1 = *(const bf16x8*)(kp + 32);
        bf16x8 kL0 = *(const bf16x8*)kq, kL1 = *(const bf16x8*)(kq + 32);
        if (hasA) {
#pragma unroll
          for (int qf = 0; qf < 2; ++qf) {
            f32x4 cA = {}, cB = {};
            cA = MFMA16(kH0, qHc[qf][0], cA); cA = MFMA16(kH1, qHc[qf][1], cA);
            cB = MFMA16(kL0, qHc[qf][0], cB); cB = MFMA16(kL1, qHc[qf][1], cB);
            cA = MFMA16(kH0, qLc[qf][0], cA); cA = MFMA16(kH1, qLc[qf][1], cA);
            f32x4 c = cA + cB;
            float s = EXP2(c[0]) + EXP2(c[1]) + EXP2(c[2]) + EXP2(c[3]);
            if (qf == 0) sum0 += s; else sum1 += s;
          }
        }
        if (hasB) {
#pragma unroll
          for (int qf = 0; qf < 2; ++qf) {
            f32x4 cA = {}, cB = {};
            cA = MFMA16(kH0, qHp[qf][0], cA); cA = MFMA16(kH1, qHp[qf][1], cA);
            cB = MFMA16(kL0, qHp[qf][0], cB); cB = MFMA16(kL1, qHp[qf][1], cB);
            cA = MFMA16(kH0, qLp[qf][0], cA); cA = MFMA16(kH1, qLp[qf][1], cA);
            f32x4 c = cA + cB;
            f32x4 p;
#pragma unroll
            for (int r = 0; r < 4; ++r)
              p[r] = EXP2(c[r]) * invqB[qf];
            *(f32x4*)&pt[w][qf * 16 + l15][(t2 << 4) + (lg << 2)] = p;
          }
        }
      }
      if (hasB) {
        const int srow = lane >> 3, scol = (lane & 7) << 2;
#pragma unroll
        for (int s = 0; s < 4; ++s) {
          const int row = (s << 3) + srow;
          f32x4 vv = *(const f32x4*)&pt[w][row][scol];
          __builtin_nontemporal_store(
              vv, (f32x4*)(attn + (zrow + sBb + row) * Sn + kbc + scol));
        }
#pragma unroll
        for (int qf = 0; qf < 2; ++qf) {
          f32x4 pa = *(const f32x4*)&pt[w][qf * 16 + l15][lg << 3];
          f32x4 pc = *(const f32x4*)&pt[w][qf * 16 + l15][(lg << 3) + 4];
          bf16x8 pbv;
#pragma unroll
          for (int e = 0; e < 4; ++e) {
            pbv[e] = (bhalf)pa[e];
            pbv[4 + e] = (bhalf)pc[e];
          }
#pragma unroll
          for (int g = 0; g < 4; ++g) {
            const bf16x8 va = *(const bf16x8*)(
                vt + ((size_t)z * Dn + g * 16 + l15) * Sn + kbc + lg * 8);
            acc[qf][g] = MFMA16(va, pbv, acc[qf][g]);
          }
        }
      }
    }

    if (hasA) {
      sum0 += __shfl_xor(sum0, 16); sum0 += __shfl_xor(sum0, 32);
      sum1 += __shfl_xor(sum1, 16); sum1 += __shfl_xor(sum1, 32);
      if (lane < 16) {
        lsum[w][l15] = sum0;
        lsum[w][16 + l15] = sum1;
      }
    }
    __syncthreads();
    if (hasA && tid < 32)
      linv[tid] =
          1.0f / (lsum[0][tid] + lsum[1][tid] + lsum[2][tid] + lsum[3][tid]);
    if (hasB) {
      float* fb = (float*)&pt[w][0][0];
      float* fb0 = (float*)&pt[0][0][0];
      float* fb1 = (float*)&pt[1][0][0];
      float* fb2 = (float*)&pt[2][0][0];
      float* fb3 = (float*)&pt[3][0][0];
#pragma unroll
      for (int qf = 0; qf < 2; ++qf) {
#pragma unroll
        for (int g = 0; g < 4; ++g)
#pragma unroll
          for (int r = 0; r < 4; ++r)
            fb[l15 * 72 + g * 16 + lg * 4 + r] = acc[qf][g][r];
        __syncthreads();
        {
          const int qq = tid >> 4, d4 = (tid & 15) << 2;
          f32x4 rs = *(const f32x4*)&fb0[qq * 72 + d4];
          rs += *(const f32x4*)&fb1[qq * 72 + d4];
          rs += *(const f32x4*)&fb2[qq * 72 + d4];
          rs += *(const f32x4*)&fb3[qq * 72 + d4];
          const size_t off =
              ((size_t)bb * Sn + sBb + qf * 16 + qq) * Cn + hh * Dn + d4;
          bf16x4 hv, lv;
#pragma unroll
          for (int e = 0; e < 4; ++e) {
            bhalf h = (bhalf)rs[e];
            hv[e] = h;
            lv[e] = (bhalf)(rs[e] - (float)h);
          }
          *(bf16x4*)(ctxH + off) = hv;
          *(bf16x4*)(ctxL + off) = lv;
        }
        __syncthreads();
      }
    } else {
      __syncthreads();
    }
    if (hasA) {
      invqB[0] = linv[l15];
      invqB[1] = linv[16 + l15];
#pragma unroll
      for (int qf = 0; qf < 2; ++qf)
#pragma unroll
        for (int sl = 0; sl < 2; ++sl) {
          qHp[qf][sl] = qHc[qf][sl];
          qLp[qf][sl] = qLc[qf][sl];
        }
      if (tau < 3)
        load_q(qhH, qhL, zrow, sB0 + ((tau + 1) << 5), l15, lg, qHc, qLc);
    }
  }
}

extern "C" void kernel_launch(void* const* d_in, const int* in_sizes, int n_in,
                              void* d_out, int out_size, void* d_ws, size_t ws_size,
                              hipStream_t stream) {
  const float* q = (const float*)d_in[0];
  const float* k = (const float*)d_in[1];
  const float* v = (const float*)d_in[2];
  const float* Wq = (const float*)d_in[3];
  const float* Wk = (const float*)d_in[4];
  const float* Wv = (const float*)d_in[5];
  const float* Wo = (const float*)d_in[6];

  float* out = (float*)d_out;                       // [B,S,C] 4M f32
  float* attn = out + (size_t)Mn * Cn;              // [B,H,S,S] 134M f32
  bhalf* vt = (bhalf*)d_out;                        // stash V^T (8MB) in out region

  bhalf* qhH = (bhalf*)d_ws;                        // 6 x 8MB = 48MB ws
  bhalf* qhL = qhH + (size_t)Mn * Cn;
  bhalf* khH = qhL + (size_t)Mn * Cn;
  bhalf* khL = khH + (size_t)Mn * Cn;
  bhalf* ctxH = khL + (size_t)Mn * Cn;
  bhalf* ctxL = ctxH + (size_t)Mn * Cn;

  dim3 gP3(Cn / 64, Mn / 64, 3);  // fused q/k/v projections, one launch
  proj_qkv<<<gP3, 256, 0, stream>>>(q, k, v, Wq, Wk, Wv, qhH, qhL, khH, khL, vt);

  attn_fused<<<Zn * (Sn / 128), 256, 0, stream>>>(qhH, qhL, khH, khL, vt, attn,
                                                  ctxH, ctxL);

  dim3 gP(Cn / 64, Mn / 64);
  proj_out<<<gP, 256, 0, stream>>>(ctxH, ctxL, Wo, out);
}